// Round 1
// baseline (275.013 us; speedup 1.0000x reference)
//
#include <hip/hip_runtime.h>
#include <math.h>

// Problem constants (B=4096, D=128 hardcoded from reference setup_inputs)
#define NB 4096
#define ND 128

#define SCALE_POS 2.0f
#define SCALE_NEG 50.0f
#define THRESH    0.7f
#define MARGIN    0.1f
#define GAMMA     0.3f
#define EPS_SELF  1e-5f

// Monotone float<->uint key: order-preserving for all non-NaN floats (incl +-inf)
__device__ __forceinline__ unsigned int fkey(float f) {
  unsigned int u = __float_as_uint(f);
  return (u & 0x80000000u) ? ~u : (u | 0x80000000u);
}
__device__ __forceinline__ float keyf(unsigned int k) {
  unsigned int u = (k & 0x80000000u) ? (k & 0x7FFFFFFFu) : ~k;
  return __uint_as_float(u);
}

// ---------------------------------------------------------------------------
// K0: per-row squared norm, init reduction keys + zero accumulators
// grid 1024 x 256 (4 waves/block, 1 wave per row)
__global__ __launch_bounds__(256) void k0_setup(
    const float* __restrict__ emb,
    unsigned long long* __restrict__ minkey, unsigned int* __restrict__ maxkey,
    float* __restrict__ sq, float* __restrict__ possum, float* __restrict__ negsum) {
  int w = threadIdx.x >> 6, lane = threadIdx.x & 63;
  int row = blockIdx.x * 4 + w;
  const float2* e2 = (const float2*)emb;
  float2 v = e2[row * 64 + lane];
  float s = v.x * v.x + v.y * v.y;
#pragma unroll
  for (int d = 1; d < 64; d <<= 1) s += __shfl_xor(s, d, 64);
  if (lane == 0) {
    sq[row] = s;
    minkey[row] = 0xFF800000FFFFFFFFULL;  // (+inf key, idx ~0)
    maxkey[row] = 0x007FFFFFu;            // -inf key
    possum[row] = 0.0f;
    negsum[row] = 0.0f;
  }
}

// ---------------------------------------------------------------------------
// K2 (pass 1): sim tile 64x64, per-row min_pos (packed with argmin idx) + max_neg
// grid (64,64) x 256 threads; LDS K-major [128][64] with XOR swizzle.
__global__ __launch_bounds__(256) void k2_pass1(
    const float* __restrict__ emb, const int* __restrict__ labels,
    unsigned long long* __restrict__ minkey, unsigned int* __restrict__ maxkey) {
  __shared__ float a_lds[128 * 64];
  __shared__ float b_lds[128 * 64];
  int tid = threadIdx.x;
  int mbase = blockIdx.y * 64, nbase = blockIdx.x * 64;

  // stage: 8 rows per iter, thread t -> row tid>>5, float4 col tid&31
  {
    int rrow = tid >> 5, c = tid & 31;
    const float4* e4 = (const float4*)emb;
    int k0 = 4 * c;
    int v = ((k0 >> 3) & 7) << 2;  // same for k0..k0+3
#pragma unroll
    for (int r = 0; r < 8; ++r) {
      int m = r * 8 + rrow;
      float4 va = e4[(size_t)(mbase + m) * 32 + c];
      float4 vb = e4[(size_t)(nbase + m) * 32 + c];
      int ms = m ^ v;
      a_lds[(k0 + 0) * 64 + ms] = va.x;
      a_lds[(k0 + 1) * 64 + ms] = va.y;
      a_lds[(k0 + 2) * 64 + ms] = va.z;
      a_lds[(k0 + 3) * 64 + ms] = va.w;
      b_lds[(k0 + 0) * 64 + ms] = vb.x;
      b_lds[(k0 + 1) * 64 + ms] = vb.y;
      b_lds[(k0 + 2) * 64 + ms] = vb.z;
      b_lds[(k0 + 3) * 64 + ms] = vb.w;
    }
  }
  __syncthreads();

  int tx = tid & 15, ty = tid >> 4;
  float acc[4][4] = {};
  for (int k8 = 0; k8 < 16; ++k8) {
    int v = (k8 & 7) << 2;
    const float* ab = &a_lds[k8 * 8 * 64 + ((4 * ty) ^ v)];
    const float* bb = &b_lds[k8 * 8 * 64 + ((4 * tx) ^ v)];
#pragma unroll
    for (int kk = 0; kk < 8; ++kk) {
      float4 a = *(const float4*)(ab + kk * 64);
      float4 b = *(const float4*)(bb + kk * 64);
#pragma unroll
      for (int i = 0; i < 4; ++i) {
        float ai = (&a.x)[i];
#pragma unroll
        for (int j = 0; j < 4; ++j) acc[i][j] += ai * (&b.x)[j];
      }
    }
  }

  // epilogue: per anchor row, reduce over this tile's 64 n's
  int labm[4], labn[4];
#pragma unroll
  for (int i = 0; i < 4; ++i) labm[i] = labels[mbase + 4 * ty + i];
#pragma unroll
  for (int j = 0; j < 4; ++j) labn[j] = labels[nbase + 4 * tx + j];

#pragma unroll
  for (int i = 0; i < 4; ++i) {
    int mg = mbase + 4 * ty + i;
    unsigned long long pk = 0xFF800000FFFFFFFFULL;
    unsigned int nk = 0x007FFFFFu;
#pragma unroll
    for (int j = 0; j < 4; ++j) {
      float s = acc[i][j];
      int ng = nbase + 4 * tx + j;
      if (labm[i] == labn[j]) {
        if (s < 1.0f - EPS_SELF) {
          unsigned long long cand = ((unsigned long long)fkey(s) << 32) | (unsigned int)ng;
          pk = pk < cand ? pk : cand;
        }
      } else {
        unsigned int ck = fkey(s);
        nk = nk > ck ? nk : ck;
      }
    }
#pragma unroll
    for (int d = 1; d < 16; d <<= 1) {
      unsigned long long po = __shfl_xor(pk, d, 64);
      pk = pk < po ? pk : po;
      unsigned int no = __shfl_xor(nk, d, 64);
      nk = nk > no ? nk : no;
    }
    if (tx == 0) {
      atomicMin(&minkey[mg], pk);
      atomicMax(&maxkey[mg], nk);
    }
  }
}

// ---------------------------------------------------------------------------
// K3: decode keys, compute validity, d_p stats (dotp, norm_p). 1 wave/row.
__global__ __launch_bounds__(256) void k3_prep(
    const float* __restrict__ emb,
    const unsigned long long* __restrict__ minkey, const unsigned int* __restrict__ maxkey,
    float* __restrict__ minposf, float* __restrict__ maxnegf,
    float* __restrict__ dotpA, float* __restrict__ normpA,
    int* __restrict__ jarr, int* __restrict__ validA) {
  int w = threadIdx.x >> 6, lane = threadIdx.x & 63;
  int i = blockIdx.x * 4 + w;
  unsigned long long mk = minkey[i];
  unsigned int xk = maxkey[i];
  float minpos = keyf((unsigned int)(mk >> 32));
  float maxneg = keyf(xk);
  int jr = (int)(mk & 0xFFFFFFFFu);
  bool valid = (maxneg + MARGIN > minpos);  // false for any inf/NaN combos
  int j = valid ? jr : i;
  const float2* e2 = (const float2*)emb;
  float2 ei = e2[(size_t)i * 64 + lane];
  float2 ej = e2[(size_t)j * 64 + lane];
  float2 dp = make_float2(ej.x - ei.x, ej.y - ei.y);
  float dtp = ei.x * dp.x + ei.y * dp.y;
  float np = dp.x * dp.x + dp.y * dp.y;
#pragma unroll
  for (int d = 1; d < 64; d <<= 1) {
    dtp += __shfl_xor(dtp, d, 64);
    np += __shfl_xor(np, d, 64);
  }
  if (lane == 0) {
    minposf[i] = minpos;
    maxnegf[i] = maxneg;
    dotpA[i] = dtp;
    normpA[i] = sqrtf(np);
    jarr[i] = j;
    validA[i] = valid ? 1 : 0;
  }
}

// ---------------------------------------------------------------------------
// K4 (pass 2): dual GEMM tile (sim and e_n.d_p) 32x64 + loss-term epilogue.
// grid (64,128) x 256 threads.
__global__ __launch_bounds__(256) void k4_pass2(
    const float* __restrict__ emb, const int* __restrict__ labels,
    const float* __restrict__ sq,
    const float* __restrict__ minposf, const float* __restrict__ maxnegf,
    const float* __restrict__ dotpA, const float* __restrict__ normpA,
    const int* __restrict__ jarr,
    float* __restrict__ possum, float* __restrict__ negsum) {
  __shared__ float ai_lds[128 * 32];
  __shared__ float dp_lds[128 * 32];
  __shared__ float b_lds[128 * 64];
  __shared__ int labn_s[64];
  __shared__ float sqn_s[64];
  int tid = threadIdx.x;
  int mbase = blockIdx.y * 32, nbase = blockIdx.x * 64;

  {
    int rrow = tid >> 5, c = tid & 31;
    const float4* e4 = (const float4*)emb;
    int k0 = 4 * c;
    int v = ((k0 >> 3) & 7) << 2;
#pragma unroll
    for (int r = 0; r < 8; ++r) {  // B tile: 64 rows
      int m = r * 8 + rrow;
      float4 vb = e4[(size_t)(nbase + m) * 32 + c];
      int ms = m ^ v;
      b_lds[(k0 + 0) * 64 + ms] = vb.x;
      b_lds[(k0 + 1) * 64 + ms] = vb.y;
      b_lds[(k0 + 2) * 64 + ms] = vb.z;
      b_lds[(k0 + 3) * 64 + ms] = vb.w;
    }
#pragma unroll
    for (int r = 0; r < 4; ++r) {  // A tile: 32 rows (e_i and d_p = e_j - e_i)
      int m = r * 8 + rrow;
      int ig = mbase + m;
      int jg = jarr[ig];
      float4 va = e4[(size_t)ig * 32 + c];
      float4 vj = e4[(size_t)jg * 32 + c];
      int ms = m ^ v;  // m<32, v<=28 -> stays in [0,32)
      ai_lds[(k0 + 0) * 32 + ms] = va.x;
      ai_lds[(k0 + 1) * 32 + ms] = va.y;
      ai_lds[(k0 + 2) * 32 + ms] = va.z;
      ai_lds[(k0 + 3) * 32 + ms] = va.w;
      dp_lds[(k0 + 0) * 32 + ms] = vj.x - va.x;
      dp_lds[(k0 + 1) * 32 + ms] = vj.y - va.y;
      dp_lds[(k0 + 2) * 32 + ms] = vj.z - va.z;
      dp_lds[(k0 + 3) * 32 + ms] = vj.w - va.w;
    }
    if (tid < 64) {
      labn_s[tid] = labels[nbase + tid];
      sqn_s[tid] = sq[nbase + tid];
    }
  }
  __syncthreads();

  int tx = tid & 15, ty = tid >> 4;
  float accs[2][4] = {};
  float accd[2][4] = {};
  for (int k8 = 0; k8 < 16; ++k8) {
    int v = (k8 & 7) << 2;
    const float* ab = &ai_lds[k8 * 8 * 32 + ((2 * ty) ^ v)];
    const float* db = &dp_lds[k8 * 8 * 32 + ((2 * ty) ^ v)];
    const float* bb = &b_lds[k8 * 8 * 64 + ((4 * tx) ^ v)];
#pragma unroll
    for (int kk = 0; kk < 8; ++kk) {
      float2 a = *(const float2*)(ab + kk * 32);
      float2 dd = *(const float2*)(db + kk * 32);
      float4 b = *(const float4*)(bb + kk * 64);
#pragma unroll
      for (int j = 0; j < 4; ++j) {
        float bj = (&b.x)[j];
        accs[0][j] += a.x * bj;
        accs[1][j] += a.y * bj;
        accd[0][j] += dd.x * bj;
        accd[1][j] += dd.y * bj;
      }
    }
  }

#pragma unroll
  for (int i = 0; i < 2; ++i) {
    int mg = mbase + 2 * ty + i;
    float mp = minposf[mg], mx = maxnegf[mg];
    float dpp = dotpA[mg], npp = normpA[mg];
    int lm = labels[mg];
    float sqm = sq[mg];
    float ps = 0.0f, ns = 0.0f;
#pragma unroll
    for (int j = 0; j < 4; ++j) {
      int nl = 4 * tx + j;
      float s = accs[i][j];
      if (lm == labn_s[nl]) {
        if (s < 1.0f - EPS_SELF && s - MARGIN < mx)
          ps += __expf(-SCALE_POS * (s - THRESH));
      } else {
        if (s + MARGIN > mp) {
          float nn = sqrtf(fmaxf(sqn_s[nl] + sqm - 2.0f * s, 1e-12f));
          float denom = fmaxf(nn, 1e-8f) * fmaxf(npp, 1e-8f);
          float reg = GAMMA * (accd[i][j] - dpp) / denom;
          ns += __expf(SCALE_NEG * (s - THRESH - reg));
        }
      }
    }
#pragma unroll
    for (int d = 1; d < 16; d <<= 1) {
      ps += __shfl_xor(ps, d, 64);
      ns += __shfl_xor(ns, d, 64);
    }
    if (tx == 0) {
      atomicAdd(&possum[mg], ps);
      atomicAdd(&negsum[mg], ns);
    }
  }
}

// ---------------------------------------------------------------------------
// K5: final row losses + mean. Single block.
__global__ __launch_bounds__(256) void k5_final(
    const float* __restrict__ possum, const float* __restrict__ negsum,
    const int* __restrict__ validA, float* __restrict__ out) {
  float local = 0.0f;
  for (int r = threadIdx.x; r < NB; r += 256) {
    if (validA[r])
      local += log1pf(possum[r]) * (1.0f / SCALE_POS) + log1pf(negsum[r]) * (1.0f / SCALE_NEG);
  }
#pragma unroll
  for (int d = 1; d < 64; d <<= 1) local += __shfl_xor(local, d, 64);
  __shared__ float partial[4];
  if ((threadIdx.x & 63) == 0) partial[threadIdx.x >> 6] = local;
  __syncthreads();
  if (threadIdx.x == 0)
    out[0] = (partial[0] + partial[1] + partial[2] + partial[3]) / (float)NB;
}

// ---------------------------------------------------------------------------
extern "C" void kernel_launch(void* const* d_in, const int* in_sizes, int n_in,
                              void* d_out, int out_size, void* d_ws, size_t ws_size,
                              hipStream_t stream) {
  const float* emb = (const float*)d_in[0];
  const int* labels = (const int*)d_in[1];
  float* out = (float*)d_out;
  char* ws = (char*)d_ws;

  unsigned long long* minkey = (unsigned long long*)(ws);            // 32 KB
  unsigned int* maxkey = (unsigned int*)(ws + 32768);                // 16 KB
  float* sq = (float*)(ws + 49152);                                  // 16 KB
  float* minposf = (float*)(ws + 65536);
  float* maxnegf = (float*)(ws + 81920);
  float* dotpA = (float*)(ws + 98304);
  float* normpA = (float*)(ws + 114688);
  int* jarr = (int*)(ws + 131072);
  int* validA = (int*)(ws + 147456);
  float* possum = (float*)(ws + 163840);
  float* negsum = (float*)(ws + 180224);  // total 192 KB of ws

  hipLaunchKernelGGL(k0_setup, dim3(NB / 4), dim3(256), 0, stream,
                     emb, minkey, maxkey, sq, possum, negsum);
  hipLaunchKernelGGL(k2_pass1, dim3(NB / 64, NB / 64), dim3(256), 0, stream,
                     emb, labels, minkey, maxkey);
  hipLaunchKernelGGL(k3_prep, dim3(NB / 4), dim3(256), 0, stream,
                     emb, minkey, maxkey, minposf, maxnegf, dotpA, normpA, jarr, validA);
  hipLaunchKernelGGL(k4_pass2, dim3(NB / 64, NB / 32), dim3(256), 0, stream,
                     emb, labels, sq, minposf, maxnegf, dotpA, normpA, jarr, possum, negsum);
  hipLaunchKernelGGL(k5_final, dim3(1), dim3(256), 0, stream,
                     possum, negsum, validA, out);
}

// Round 2
// 99.420 us; speedup vs baseline: 2.7662x; 2.7662x over previous
//
#include <hip/hip_runtime.h>
#include <math.h>

#define NB 4096
#define ND 128

#define SCALE_POS 2.0f
#define SCALE_NEG 50.0f
#define THRESH    0.7f
#define MARGIN    0.1f
#define GAMMA     0.3f
#define EPS_SELF  1e-5f

typedef __attribute__((ext_vector_type(8))) short s16x8;
typedef __attribute__((ext_vector_type(4))) float f32x4;

// Monotone float<->uint key (order-preserving incl +-inf)
__device__ __forceinline__ unsigned int fkey(float f) {
  unsigned int u = __float_as_uint(f);
  return (u & 0x80000000u) ? ~u : (u | 0x80000000u);
}
__device__ __forceinline__ float keyf(unsigned int k) {
  unsigned int u = (k & 0x80000000u) ? (k & 0x7FFFFFFFu) : ~k;
  return __uint_as_float(u);
}

__device__ __forceinline__ short f2bf(float x) {  // RNE truncate to bf16
  unsigned u = __float_as_uint(x);
  unsigned r = (u + 0x7FFFu + ((u >> 16) & 1u)) >> 16;
  return (short)r;
}
__device__ __forceinline__ float bf2f(short h) {
  return __uint_as_float(((unsigned)(unsigned short)h) << 16);
}

// ---------------------------------------------------------------------------
// K1: fp32 -> bf16 hi/lo split; also init reduction keys. 512 blocks x 256.
__global__ __launch_bounds__(256) void k1_convert(
    const float* __restrict__ emb, short* __restrict__ ehi, short* __restrict__ elo,
    unsigned long long* __restrict__ minkey, unsigned int* __restrict__ maxkey) {
  int t = blockIdx.x * 256 + threadIdx.x;  // 131072 threads, 4 floats each
  float4 v = ((const float4*)emb)[t];
  short4 h, l;
  {
    float x;
    x = v.x; h.x = f2bf(x); l.x = f2bf(x - bf2f(h.x));
    x = v.y; h.y = f2bf(x); l.y = f2bf(x - bf2f(h.y));
    x = v.z; h.z = f2bf(x); l.z = f2bf(x - bf2f(h.z));
    x = v.w; h.w = f2bf(x); l.w = f2bf(x - bf2f(h.w));
  }
  ((short4*)ehi)[t] = h;
  ((short4*)elo)[t] = l;
  if (t < NB) {
    minkey[t] = 0xFF800000FFFFFFFFULL;  // (+inf key, idx ~0)
    maxkey[t] = 0x007FFFFFu;            // -inf key
  }
}

// ---------------------------------------------------------------------------
// K2: Gram matrix via split-bf16 MFMA. Block 128x128 (4 waves, 64x64 each).
// Writes sim (fp32) + per-row packed argmin(pos) / max(neg) atomics.
__global__ __launch_bounds__(256) void k2_gram(
    const short* __restrict__ ehi, const short* __restrict__ elo,
    const int* __restrict__ labels,
    float* __restrict__ sim,
    unsigned long long* __restrict__ minkey, unsigned int* __restrict__ maxkey) {
  int tid = threadIdx.x;
  int w = tid >> 6, l = tid & 63;
  int lm16 = l & 15, lg = l >> 4;
  int mbase = blockIdx.y * 128 + (w >> 1) * 64;
  int nbase = blockIdx.x * 128 + (w & 1) * 64;

  f32x4 acc[4][4] = {};

  for (int s = 0; s < 4; ++s) {
    int koff = s * 32 + lg * 8;
    s16x8 ah[4], alo[4], bh[4], blo[4];
#pragma unroll
    for (int t = 0; t < 4; ++t) {
      size_t ra = (size_t)(mbase + t * 16 + lm16) * ND + koff;
      size_t rb = (size_t)(nbase + t * 16 + lm16) * ND + koff;
      ah[t]  = *(const s16x8*)(ehi + ra);
      alo[t] = *(const s16x8*)(elo + ra);
      bh[t]  = *(const s16x8*)(ehi + rb);
      blo[t] = *(const s16x8*)(elo + rb);
    }
#pragma unroll
    for (int ti = 0; ti < 4; ++ti)
#pragma unroll
      for (int tj = 0; tj < 4; ++tj) {
        acc[ti][tj] = __builtin_amdgcn_mfma_f32_16x16x32_bf16(ah[ti], bh[tj], acc[ti][tj], 0, 0, 0);
        acc[ti][tj] = __builtin_amdgcn_mfma_f32_16x16x32_bf16(ah[ti], blo[tj], acc[ti][tj], 0, 0, 0);
        acc[ti][tj] = __builtin_amdgcn_mfma_f32_16x16x32_bf16(alo[ti], bh[tj], acc[ti][tj], 0, 0, 0);
      }
  }

  int labn[4];
#pragma unroll
  for (int tj = 0; tj < 4; ++tj) labn[tj] = labels[nbase + tj * 16 + lm16];

#pragma unroll
  for (int ti = 0; ti < 4; ++ti) {
#pragma unroll
    for (int r = 0; r < 4; ++r) {
      int m = mbase + ti * 16 + lg * 4 + r;
      int lm = labels[m];
      unsigned long long pk = 0xFF800000FFFFFFFFULL;
      unsigned int nk = 0x007FFFFFu;
#pragma unroll
      for (int tj = 0; tj < 4; ++tj) {
        float sv = acc[ti][tj][r];
        int n = nbase + tj * 16 + lm16;
        bool diag = (n == m);
        if (diag) sv = 1.0f;  // true sim[i,i]=1 (unit rows); keeps ref's value-based exclusion exact
        sim[(size_t)m * NB + n] = sv;
        if (lm == labn[tj]) {
          if (!diag && sv < 1.0f - EPS_SELF) {
            unsigned long long cand = ((unsigned long long)fkey(sv) << 32) | (unsigned int)n;
            pk = pk < cand ? pk : cand;
          }
        } else {
          unsigned int ck = fkey(sv);
          nk = nk > ck ? nk : ck;
        }
      }
#pragma unroll
      for (int d = 1; d < 16; d <<= 1) {
        unsigned long long po = __shfl_xor(pk, d, 64);
        pk = pk < po ? pk : po;
        unsigned int no = __shfl_xor(nk, d, 64);
        nk = nk > no ? nk : no;
      }
      if (lm16 == 0) {
        atomicMin(&minkey[m], pk);
        atomicMax(&maxkey[m], nk);
      }
    }
  }
}

// ---------------------------------------------------------------------------
// K3: decode keys -> minpos/maxneg/valid/j, d_p stats from sim identities.
__global__ __launch_bounds__(256) void k3_prep(
    const unsigned long long* __restrict__ minkey, const unsigned int* __restrict__ maxkey,
    float* __restrict__ minposf, float* __restrict__ maxnegf,
    float* __restrict__ dppA, float* __restrict__ nppA,
    int* __restrict__ jarr, int* __restrict__ validA) {
  int i = blockIdx.x * 256 + threadIdx.x;
  unsigned long long mk = minkey[i];
  float minpos = keyf((unsigned int)(mk >> 32));
  float maxneg = keyf(maxkey[i]);
  bool valid = (maxneg + MARGIN > minpos);
  int j = valid ? (int)(mk & 0xFFFFFFFFu) : i;
  minposf[i] = minpos;
  maxnegf[i] = maxneg;
  jarr[i] = j;
  validA[i] = valid ? 1 : 0;
  // e_i . d_p = sim[i,j] - 1 ; ||d_p|| = sqrt(2 - 2 sim[i,j])  (unit-norm rows)
  dppA[i] = minpos - 1.0f;
  nppA[i] = fmaxf(sqrtf(fmaxf(2.0f - 2.0f * minpos, 1e-12f)), 1e-8f);
}

// ---------------------------------------------------------------------------
// K4: per-anchor streaming pass over sim[i,:], sim[j,:]. One block per row.
__global__ __launch_bounds__(256) void k4_row(
    const float* __restrict__ sim, const int* __restrict__ labels,
    const float* __restrict__ minposf, const float* __restrict__ maxnegf,
    const float* __restrict__ dppA, const float* __restrict__ nppA,
    const int* __restrict__ jarr, const int* __restrict__ validA,
    float* __restrict__ rowloss) {
  int i = blockIdx.x;
  int tid = threadIdx.x;
  if (!validA[i]) {
    if (tid == 0) rowloss[i] = 0.0f;
    return;
  }
  int j = jarr[i];
  float mp = minposf[i], mx = maxnegf[i];
  float dpp = dppA[i], inpp = 1.0f / nppA[i];
  int lm = labels[i];
  const float4* sI = (const float4*)(sim + (size_t)i * NB);
  const float4* sJ = (const float4*)(sim + (size_t)j * NB);
  const int4* ln4 = (const int4*)labels;
  float ps = 0.0f, ns = 0.0f;
  for (int c = tid; c < NB / 4; c += 256) {
    float4 a = sI[c];
    float4 b = sJ[c];
    int4 lb = ln4[c];
#pragma unroll
    for (int e = 0; e < 4; ++e) {
      float s = (&a.x)[e];
      int ln = (&lb.x)[e];
      if (ln == lm) {
        if (s < 1.0f - EPS_SELF && s - MARGIN < mx)
          ps += __expf(-SCALE_POS * (s - THRESH));
      } else if (s + MARGIN > mp) {
        float sj = (&b.x)[e];
        float nn = fmaxf(sqrtf(fmaxf(2.0f - 2.0f * s, 1e-12f)), 1e-8f);
        float rg = GAMMA * (sj - s - dpp) * inpp * __builtin_amdgcn_rcpf(nn);
        ns += __expf(SCALE_NEG * (s - THRESH - rg));
      }
    }
  }
#pragma unroll
  for (int d = 1; d < 64; d <<= 1) {
    ps += __shfl_xor(ps, d, 64);
    ns += __shfl_xor(ns, d, 64);
  }
  __shared__ float redp[4], redn[4];
  if ((tid & 63) == 0) {
    redp[tid >> 6] = ps;
    redn[tid >> 6] = ns;
  }
  __syncthreads();
  if (tid == 0) {
    float tp = redp[0] + redp[1] + redp[2] + redp[3];
    float tn = redn[0] + redn[1] + redn[2] + redn[3];
    rowloss[i] = log1pf(tp) * (1.0f / SCALE_POS) + log1pf(tn) * (1.0f / SCALE_NEG);
  }
}

// ---------------------------------------------------------------------------
// K5: mean over rows. Single block.
__global__ __launch_bounds__(256) void k5_final(
    const float* __restrict__ rowloss, float* __restrict__ out) {
  float local = 0.0f;
  for (int r = threadIdx.x; r < NB; r += 256) local += rowloss[r];
#pragma unroll
  for (int d = 1; d < 64; d <<= 1) local += __shfl_xor(local, d, 64);
  __shared__ float partial[4];
  if ((threadIdx.x & 63) == 0) partial[threadIdx.x >> 6] = local;
  __syncthreads();
  if (threadIdx.x == 0)
    out[0] = (partial[0] + partial[1] + partial[2] + partial[3]) / (float)NB;
}

// ---------------------------------------------------------------------------
extern "C" void kernel_launch(void* const* d_in, const int* in_sizes, int n_in,
                              void* d_out, int out_size, void* d_ws, size_t ws_size,
                              hipStream_t stream) {
  const float* emb = (const float*)d_in[0];
  const int* labels = (const int*)d_in[1];
  float* out = (float*)d_out;
  char* ws = (char*)d_ws;

  float* sim = (float*)ws;                      // 64 MB
  char* base = ws + (size_t)NB * NB * 4;
  unsigned long long* minkey = (unsigned long long*)(base);           // 32 KB
  unsigned int* maxkey = (unsigned int*)(base + 32768);               // 16 KB
  float* minposf = (float*)(base + 49152);
  float* maxnegf = (float*)(base + 65536);
  float* dppA = (float*)(base + 81920);
  float* nppA = (float*)(base + 98304);
  int* jarr = (int*)(base + 114688);
  int* validA = (int*)(base + 131072);
  float* rowloss = (float*)(base + 147456);
  short* ehi = (short*)(base + 163840);                               // 1 MB
  short* elo = (short*)(base + 163840 + 1048576);                     // 1 MB

  hipLaunchKernelGGL(k1_convert, dim3(NB * ND / 4 / 256), dim3(256), 0, stream,
                     emb, ehi, elo, minkey, maxkey);
  hipLaunchKernelGGL(k2_gram, dim3(NB / 128, NB / 128), dim3(256), 0, stream,
                     ehi, elo, labels, sim, minkey, maxkey);
  hipLaunchKernelGGL(k3_prep, dim3(NB / 256), dim3(256), 0, stream,
                     minkey, maxkey, minposf, maxnegf, dppA, nppA, jarr, validA);
  hipLaunchKernelGGL(k4_row, dim3(NB), dim3(256), 0, stream,
                     sim, labels, minposf, maxnegf, dppA, nppA, jarr, validA, rowloss);
  hipLaunchKernelGGL(k5_final, dim3(1), dim3(256), 0, stream, rowloss, out);
}